// Round 1
// baseline (4240.490 us; speedup 1.0000x reference)
//
#include <hip/hip_runtime.h>

#define D_MODEL 1024
#define NH 16
#define DHD 64
#define QLEN 1024
#define MLEN 1024
#define KLEN 2048
#define DFF 4096
#define WSZ 1000   // attention band width: j - i in [25, 1024]

// ================= GEMM NN: C[M,N] = A[M,Kd] @ B[Kd,N] (+ U) =================
// A row-major ld=Kd. B row-major ld=ldB. C row-major ld=ldC. U (optional) same layout as C.
__global__ __launch_bounds__(256) void gemm_nn_f32(
    const float* __restrict__ A, const float* __restrict__ B,
    float* __restrict__ C, const float* __restrict__ U,
    int M, int N, int Kd, int ldB, int ldC,
    long long sA, long long sB, long long sC)
{
    int bz = blockIdx.z;
    A += (long long)bz * sA;
    B += (long long)bz * sB;
    C += (long long)bz * sC;
    const float* Up = U ? (U + (long long)bz * sC) : nullptr;

    __shared__ float As[16][65];   // A tile transposed [k][m], padded
    __shared__ float Bs[16][64];   // B tile [k][n]

    int m0 = blockIdx.y * 64;
    int n0 = blockIdx.x * 64;
    int t  = threadIdx.x;
    int tx = t & 15, ty = t >> 4;

    float acc[4][4] = {};

    for (int k0 = 0; k0 < Kd; k0 += 16) {
        {   // load A tile 64x16 -> As[k][m]
            int k = t & 15, mr = t >> 4;
            #pragma unroll
            for (int i = 0; i < 4; i++)
                As[k][mr + i * 16] = A[(long long)(m0 + mr + i * 16) * Kd + k0 + k];
        }
        {   // load B tile 16x64 -> Bs[k][n]
            int n = t & 63, kr = t >> 6;
            #pragma unroll
            for (int i = 0; i < 4; i++)
                Bs[kr + i * 4][n] = B[(long long)(k0 + kr + i * 4) * ldB + n0 + n];
        }
        __syncthreads();
        #pragma unroll
        for (int kk = 0; kk < 16; kk++) {
            float a[4], b[4];
            #pragma unroll
            for (int i = 0; i < 4; i++) a[i] = As[kk][ty * 4 + i];
            #pragma unroll
            for (int j = 0; j < 4; j++) b[j] = Bs[kk][tx * 4 + j];
            #pragma unroll
            for (int i = 0; i < 4; i++)
                #pragma unroll
                for (int j = 0; j < 4; j++)
                    acc[i][j] += a[i] * b[j];
        }
        __syncthreads();
    }
    #pragma unroll
    for (int i = 0; i < 4; i++) {
        int m = m0 + ty * 4 + i;
        #pragma unroll
        for (int j = 0; j < 4; j++) {
            int n = n0 + tx * 4 + j;
            float v = acc[i][j];
            if (Up) v += Up[(long long)m * ldC + n];
            C[(long long)m * ldC + n] = v;
        }
    }
}

// ============ GEMM NT: C[M,N] = A[M,Kd] @ B[N,Kd]^T + bias[n], opt relu ============
__global__ __launch_bounds__(256) void gemm_nt_f32(
    const float* __restrict__ A, const float* __restrict__ B,
    float* __restrict__ C, const float* __restrict__ bias,
    int M, int N, int Kd, int relu)
{
    __shared__ float As[16][65];
    __shared__ float Bs[16][65];

    int m0 = blockIdx.y * 64;
    int n0 = blockIdx.x * 64;
    int t  = threadIdx.x;
    int tx = t & 15, ty = t >> 4;

    float acc[4][4] = {};

    for (int k0 = 0; k0 < Kd; k0 += 16) {
        {
            int k = t & 15, mr = t >> 4;
            #pragma unroll
            for (int i = 0; i < 4; i++)
                As[k][mr + i * 16] = A[(long long)(m0 + mr + i * 16) * Kd + k0 + k];
        }
        {
            int k = t & 15, nr = t >> 4;
            #pragma unroll
            for (int i = 0; i < 4; i++)
                Bs[k][nr + i * 16] = B[(long long)(n0 + nr + i * 16) * Kd + k0 + k];
        }
        __syncthreads();
        #pragma unroll
        for (int kk = 0; kk < 16; kk++) {
            float a[4], b[4];
            #pragma unroll
            for (int i = 0; i < 4; i++) a[i] = As[kk][ty * 4 + i];
            #pragma unroll
            for (int j = 0; j < 4; j++) b[j] = Bs[kk][tx * 4 + j];
            #pragma unroll
            for (int i = 0; i < 4; i++)
                #pragma unroll
                for (int j = 0; j < 4; j++)
                    acc[i][j] += a[i] * b[j];
        }
        __syncthreads();
    }
    #pragma unroll
    for (int i = 0; i < 4; i++) {
        int m = m0 + ty * 4 + i;
        #pragma unroll
        for (int j = 0; j < 4; j++) {
            int n = n0 + tx * 4 + j;
            float v = acc[i][j] + bias[n];
            if (relu) v = fmaxf(v, 0.0f);
            C[(long long)m * N + n] = v;
        }
    }
}

// ================= fused banded attention =================
// One block per (query i, head n, batch b). Window: j = i+25 .. i+1024 (exactly 1000 keys).
// BD via rel_shift algebra: r_k column p = 1048 + w for window offset w.
__global__ __launch_bounds__(256) void attn_kernel(
    const float* __restrict__ WH,   // (B, 3072, KLEN): rows [0,1024) q, [1024,2048) k, [2048,3072) v
    const float* __restrict__ RK,   // (1024, KLEN)
    const float* __restrict__ rwb,  // (16,64)
    const float* __restrict__ rrb,  // (16,64)
    float* __restrict__ AV)         // (B, 1024, QLEN)
{
    int i = blockIdx.x;
    int n = blockIdx.y;
    int b = blockIdx.z;
    const float scale = 0.125f;  // 1/sqrt(64)

    __shared__ float qw[DHD], qr[DHD];
    __shared__ float sc[WSZ];
    __shared__ float red[256];
    __shared__ float smax, ssum;

    int t = threadIdx.x;
    const float* whb = WH + (long long)b * 3072 * KLEN;

    if (t < DHD) {
        float qv = whb[(long long)(n * DHD + t) * KLEN + (MLEN + i)];
        qw[t] = qv + rwb[n * DHD + t];
        qr[t] = qv + rrb[n * DHD + t];
    }
    __syncthreads();

    const float* kbase = whb + (long long)(1024 + n * DHD) * KLEN;
    const float* rbase = RK + (long long)(n * DHD) * KLEN;
    int jlo = i + 25;

    // scores over the band
    for (int w = t; w < WSZ; w += 256) {
        int j = jlo + w;
        int p = 1048 + w;
        float s = 0.0f;
        #pragma unroll 8
        for (int dh = 0; dh < DHD; dh++) {
            s += qw[dh] * kbase[(long long)dh * KLEN + j];
            s += qr[dh] * rbase[(long long)dh * KLEN + p];
        }
        sc[w] = s * scale;
    }
    __syncthreads();

    // max
    float lm = -1e30f;
    for (int w = t; w < WSZ; w += 256) lm = fmaxf(lm, sc[w]);
    red[t] = lm; __syncthreads();
    for (int s2 = 128; s2 > 0; s2 >>= 1) {
        if (t < s2) red[t] = fmaxf(red[t], red[t + s2]);
        __syncthreads();
    }
    if (t == 0) smax = red[0];
    __syncthreads();
    float mx = smax;

    // exp + sum
    float ls = 0.0f;
    for (int w = t; w < WSZ; w += 256) {
        float e = __expf(sc[w] - mx);
        sc[w] = e;
        ls += e;
    }
    red[t] = ls; __syncthreads();
    for (int s2 = 128; s2 > 0; s2 >>= 1) {
        if (t < s2) red[t] += red[t + s2];
        __syncthreads();
    }
    if (t == 0) ssum = red[0];
    __syncthreads();
    float rinv = 1.0f / ssum;

    // PV: thread t -> dh = t>>2, partial g = t&3 (4 consecutive lanes read consecutive j)
    int dh = t >> 2, g = t & 3;
    const float* vrow = whb + (long long)(2048 + n * DHD + dh) * KLEN;
    float accv = 0.0f;
    for (int w = g; w < WSZ; w += 4) accv += sc[w] * vrow[jlo + w];
    __syncthreads();
    red[t] = accv;  // red[dh*4 + g]
    __syncthreads();
    if (t < DHD) {
        float r = (red[t * 4] + red[t * 4 + 1] + red[t * 4 + 2] + red[t * 4 + 3]) * rinv;
        AV[((long long)b * 1024 + n * DHD + t) * QLEN + i] = r;
    }
}

// ================= LN1: h[b,i,:] = LN_d(attn_out + b_o + z), transpose to token-major ==========
__global__ __launch_bounds__(256) void ln1_kernel(
    const float* __restrict__ AO,  // (B,1024,Q)
    const float* __restrict__ bo,  // (1024)
    const float* __restrict__ Z,   // (B,1024,Q)
    float* __restrict__ H)         // (B,Q,1024)
{
    int i = blockIdx.x, b = blockIdx.y, t = threadIdx.x;
    __shared__ float xs[D_MODEL];
    __shared__ float red[256];
    __shared__ float smu, srstd;
    long long base = (long long)b * D_MODEL * QLEN;

    float lsum = 0.0f;
    for (int d = t; d < D_MODEL; d += 256) {
        float v = AO[base + (long long)d * QLEN + i] + bo[d] + Z[base + (long long)d * QLEN + i];
        xs[d] = v;
        lsum += v;
    }
    red[t] = lsum; __syncthreads();
    for (int s2 = 128; s2 > 0; s2 >>= 1) { if (t < s2) red[t] += red[t + s2]; __syncthreads(); }
    if (t == 0) smu = red[0] * (1.0f / D_MODEL);
    __syncthreads();
    float mu = smu;

    float lq = 0.0f;
    for (int d = t; d < D_MODEL; d += 256) { float c = xs[d] - mu; lq += c * c; }
    red[t] = lq; __syncthreads();
    for (int s2 = 128; s2 > 0; s2 >>= 1) { if (t < s2) red[t] += red[t + s2]; __syncthreads(); }
    if (t == 0) srstd = rsqrtf(red[0] * (1.0f / D_MODEL) + 1e-5f);
    __syncthreads();
    float rstd = srstd;

    for (int d = t; d < D_MODEL; d += 256)
        H[base + (long long)i * D_MODEL + d] = (xs[d] - mu) * rstd;
}

// ================= LN2: out[b,d,i] = LN_d(ff2 + h)[b,i,d] (writes transposed) =================
__global__ __launch_bounds__(256) void ln2_kernel(
    const float* __restrict__ F2,  // (B,Q,1024)
    const float* __restrict__ H,   // (B,Q,1024)
    float* __restrict__ OUT)       // (B,1024,Q)
{
    int i = blockIdx.x, b = blockIdx.y, t = threadIdx.x;
    __shared__ float xs[D_MODEL];
    __shared__ float red[256];
    __shared__ float smu, srstd;
    long long base = (long long)b * D_MODEL * QLEN;

    float lsum = 0.0f;
    for (int d = t; d < D_MODEL; d += 256) {
        float v = F2[base + (long long)i * D_MODEL + d] + H[base + (long long)i * D_MODEL + d];
        xs[d] = v;
        lsum += v;
    }
    red[t] = lsum; __syncthreads();
    for (int s2 = 128; s2 > 0; s2 >>= 1) { if (t < s2) red[t] += red[t + s2]; __syncthreads(); }
    if (t == 0) smu = red[0] * (1.0f / D_MODEL);
    __syncthreads();
    float mu = smu;

    float lq = 0.0f;
    for (int d = t; d < D_MODEL; d += 256) { float c = xs[d] - mu; lq += c * c; }
    red[t] = lq; __syncthreads();
    for (int s2 = 128; s2 > 0; s2 >>= 1) { if (t < s2) red[t] += red[t + s2]; __syncthreads(); }
    if (t == 0) srstd = rsqrtf(red[0] * (1.0f / D_MODEL) + 1e-5f);
    __syncthreads();
    float rstd = srstd;

    for (int d = t; d < D_MODEL; d += 256)
        OUT[base + (long long)d * QLEN + i] = (xs[d] - mu) * rstd;
}

// ================= launch =================
extern "C" void kernel_launch(void* const* d_in, const int* in_sizes, int n_in,
                              void* d_out, int out_size, void* d_ws, size_t ws_size,
                              hipStream_t stream) {
    const float* z    = (const float*)d_in[0];   // (2,1024,1024)
    const float* zh   = (const float*)d_in[1];   // (2,1024,1024)
    const float* u    = (const float*)d_in[2];   // (2,3072,2048)
    const float* pos  = (const float*)d_in[3];   // (1024,2048)
    const float* Wqkv = (const float*)d_in[4];   // (3072,1024)
    const float* Wr   = (const float*)d_in[5];   // (1024,1024)
    const float* rwb  = (const float*)d_in[6];   // (16,64)
    const float* rrb  = (const float*)d_in[7];   // (16,64)
    const float* Wo   = (const float*)d_in[8];   // (1024,1024)
    const float* bo   = (const float*)d_in[9];   // (1024)
    const float* Wff1 = (const float*)d_in[10];  // (4096,1024)
    const float* bff1 = (const float*)d_in[11];  // (4096)
    const float* Wff2 = (const float*)d_in[12];  // (1024,4096)
    const float* bff2 = (const float*)d_in[13];  // (1024)
    float* out = (float*)d_out;
    float* ws  = (float*)d_ws;

    // workspace layout (floats)
    float* wh = ws;                       // (2,3072,2048) = 12582912
    float* rk = ws + 12582912;            // (1024,2048)   =  2097152
    float* av = ws + 14680064;            // (2,1024,1024) =  2097152
    float* ao = ws + 16777216;            // (2,1024,1024) =  2097152
    float* h  = ws + 18874368;            // (2,1024,1024) =  2097152
    float* f1 = ws + 20971520;            // (2,1024,4096) =  8388608
    float* f2 = ws + 29360128;            // (2,1024,1024) =  2097152

    const long long sZ  = (long long)D_MODEL * QLEN;        // 1M: z / z_hist batch stride
    const long long sWH = (long long)3072 * KLEN;           // wh / u batch stride
    const long long s1M = (long long)D_MODEL * QLEN;

    // w_heads left half  (keys from history): wh[:, :, 0:1024] = Wqkv @ z_hist + u[:, :, 0:1024]
    gemm_nn_f32<<<dim3(16, 48, 2), 256, 0, stream>>>(
        Wqkv, zh, wh, u, 3072, 1024, 1024, /*ldB*/1024, /*ldC*/2048, 0LL, sZ, sWH);
    // w_heads right half (current): wh[:, :, 1024:2048] = Wqkv @ z + u[:, :, 1024:2048]
    gemm_nn_f32<<<dim3(16, 48, 2), 256, 0, stream>>>(
        Wqkv, z, wh + 1024, u + 1024, 3072, 1024, 1024, 1024, 2048, 0LL, sZ, sWH);
    // r_k = Wr @ pos_emb
    gemm_nn_f32<<<dim3(32, 16, 1), 256, 0, stream>>>(
        Wr, pos, rk, nullptr, 1024, 2048, 1024, 2048, 2048, 0LL, 0LL, 0LL);
    // fused banded attention -> av (B,1024,Q)
    attn_kernel<<<dim3(1024, 16, 2), 256, 0, stream>>>(wh, rk, rwb, rrb, av);
    // attn_out = Wo @ av   (bias b_o folded into LN1)
    gemm_nn_f32<<<dim3(16, 16, 2), 256, 0, stream>>>(
        Wo, av, ao, nullptr, 1024, 1024, 1024, 1024, 1024, 0LL, s1M, s1M);
    // h = LN_d(ao + b_o + z), token-major
    ln1_kernel<<<dim3(1024, 2), 256, 0, stream>>>(ao, bo, z, h);
    // f1 = relu(h @ Wff1^T + bff1) : M=2048 tokens, N=4096
    gemm_nt_f32<<<dim3(64, 32, 1), 256, 0, stream>>>(h, Wff1, f1, bff1, 2048, 4096, 1024, 1);
    // f2 = f1 @ Wff2^T + bff2 : M=2048, N=1024
    gemm_nt_f32<<<dim3(16, 32, 1), 256, 0, stream>>>(f1, Wff2, f2, bff2, 2048, 1024, 4096, 0);
    // out = LN_d(f2 + h), transposed to (B, D, Q)
    ln2_kernel<<<dim3(1024, 2), 256, 0, stream>>>(f2, h, out);
}

// Round 2
// 1476.683 us; speedup vs baseline: 2.8716x; 2.8716x over previous
//
#include <hip/hip_runtime.h>

#define D_MODEL 1024
#define QLEN 1024
#define MLEN 1024
#define KLEN 2048

typedef __bf16 bf16x8 __attribute__((ext_vector_type(8)));
typedef float f32x4 __attribute__((ext_vector_type(4)));

// ================= GEMM NN: C[M,N] = A[M,Kd] @ B[Kd,N] (+ U) =================
__global__ __launch_bounds__(256) void gemm_nn_f32(
    const float* __restrict__ A, const float* __restrict__ B,
    float* __restrict__ C, const float* __restrict__ U,
    int M, int N, int Kd, int ldB, int ldC, int ldU,
    long long sA, long long sB, long long sC)
{
    int bz = blockIdx.z;
    A += (long long)bz * sA;
    B += (long long)bz * sB;
    C += (long long)bz * sC;
    const float* Up = U ? (U + (long long)bz * ((long long)M * ldU)) : nullptr;

    __shared__ float As[16][65];
    __shared__ float Bs[16][64];

    int m0 = blockIdx.y * 64;
    int n0 = blockIdx.x * 64;
    int t  = threadIdx.x;
    int tx = t & 15, ty = t >> 4;

    float acc[4][4] = {};

    for (int k0 = 0; k0 < Kd; k0 += 16) {
        {
            int k = t & 15, mr = t >> 4;
            #pragma unroll
            for (int i = 0; i < 4; i++)
                As[k][mr + i * 16] = A[(long long)(m0 + mr + i * 16) * Kd + k0 + k];
        }
        {
            int n = t & 63, kr = t >> 6;
            #pragma unroll
            for (int i = 0; i < 4; i++)
                Bs[kr + i * 4][n] = B[(long long)(k0 + kr + i * 4) * ldB + n0 + n];
        }
        __syncthreads();
        #pragma unroll
        for (int kk = 0; kk < 16; kk++) {
            float a[4], b[4];
            #pragma unroll
            for (int i = 0; i < 4; i++) a[i] = As[kk][ty * 4 + i];
            #pragma unroll
            for (int j = 0; j < 4; j++) b[j] = Bs[kk][tx * 4 + j];
            #pragma unroll
            for (int i = 0; i < 4; i++)
                #pragma unroll
                for (int j = 0; j < 4; j++)
                    acc[i][j] += a[i] * b[j];
        }
        __syncthreads();
    }
    #pragma unroll
    for (int i = 0; i < 4; i++) {
        int m = m0 + ty * 4 + i;
        #pragma unroll
        for (int j = 0; j < 4; j++) {
            int n = n0 + tx * 4 + j;
            float v = acc[i][j];
            if (Up) v += Up[(long long)m * ldU + n];
            C[(long long)m * ldC + n] = v;
        }
    }
}

// ============ GEMM NT: C[M,N] = A[M,Kd] @ B[N,Kd]^T + bias[n], opt relu ============
__global__ __launch_bounds__(256) void gemm_nt_f32(
    const float* __restrict__ A, const float* __restrict__ B,
    float* __restrict__ C, const float* __restrict__ bias,
    int M, int N, int Kd, int relu)
{
    __shared__ float As[16][65];
    __shared__ float Bs[16][65];

    int m0 = blockIdx.y * 64;
    int n0 = blockIdx.x * 64;
    int t  = threadIdx.x;
    int tx = t & 15, ty = t >> 4;

    float acc[4][4] = {};

    for (int k0 = 0; k0 < Kd; k0 += 16) {
        {
            int k = t & 15, mr = t >> 4;
            #pragma unroll
            for (int i = 0; i < 4; i++)
                As[k][mr + i * 16] = A[(long long)(m0 + mr + i * 16) * Kd + k0 + k];
        }
        {
            int k = t & 15, nr = t >> 4;
            #pragma unroll
            for (int i = 0; i < 4; i++)
                Bs[k][nr + i * 16] = B[(long long)(n0 + nr + i * 16) * Kd + k0 + k];
        }
        __syncthreads();
        #pragma unroll
        for (int kk = 0; kk < 16; kk++) {
            float a[4], b[4];
            #pragma unroll
            for (int i = 0; i < 4; i++) a[i] = As[kk][ty * 4 + i];
            #pragma unroll
            for (int j = 0; j < 4; j++) b[j] = Bs[kk][tx * 4 + j];
            #pragma unroll
            for (int i = 0; i < 4; i++)
                #pragma unroll
                for (int j = 0; j < 4; j++)
                    acc[i][j] += a[i] * b[j];
        }
        __syncthreads();
    }
    #pragma unroll
    for (int i = 0; i < 4; i++) {
        int m = m0 + ty * 4 + i;
        #pragma unroll
        for (int j = 0; j < 4; j++) {
            int n = n0 + tx * 4 + j;
            float v = acc[i][j] + bias[n];
            if (relu) v = fmaxf(v, 0.0f);
            C[(long long)m * N + n] = v;
        }
    }
}

// zero rk pad columns [2048, 2112) for all 1024 rows
__global__ __launch_bounds__(256) void pad_zero(float* __restrict__ rk) {
    int t = blockIdx.x * 256 + threadIdx.x;      // 65536 threads
    int row = t >> 6, c = t & 63;
    rk[(long long)row * 2112 + 2048 + c] = 0.0f;
}

// ================= MFMA flash attention over the fixed band j-i in [25,1024] =================
// block = (b, head, 64-query tile). 4 waves, wave w owns q rows [w*16, w*16+16).
// 17 key tiles of 64 starting at j0 = i0 + 64*kt. BD via Toeplitz lookup p = j-i+1023.
__global__ __launch_bounds__(256) void attn_mfma(
    const float* __restrict__ WH,   // (B,3072,2048): [0,1024) q, [1024,2048) k, [2048,3072) v
    const float* __restrict__ RK,   // (1024,2112) padded, cols >=2048 zero
    const float* __restrict__ rwb, const float* __restrict__ rrb,
    float* __restrict__ AV)         // (B,1024,1024)
{
    __shared__ __bf16 KT[64][72];    // K^T tile: [j][dh]
    __shared__ __bf16 RT[128][72];   // r_k^T tile: [p][dh]
    __shared__ __bf16 VS[64][72];    // V tile natural: [dh][j]
    __shared__ __bf16 PS[64][72];    // P tile [q][j]; prologue: QwT
    __shared__ __bf16 BT[64][136];   // BD_raw tile [q][pi]; prologue: QrT

    // XCD-aware decode: all 16 q-tiles of one (b,head) land on one XCD
    const int d = blockIdx.x;            // 0..511
    const int xcd = d & 7, idx = d >> 3; // idx 0..63
    const int qt = idx & 15;
    const int gq = xcd + 8 * (idx >> 4); // 0..31
    const int b = gq >> 4, n = gq & 15;
    const int i0 = qt * 64;

    const int t = threadIdx.x;
    const int lane = t & 63, w = t >> 6;
    const int l15 = lane & 15, lg = lane >> 4;

    const float* whb = WH + (long long)b * 3072 * 2048;
    const float* qb = whb + (long long)(n * 64) * 2048;
    const float* kb = whb + (long long)(1024 + n * 64) * 2048;
    const float* vb = whb + (long long)(2048 + n * 64) * 2048;
    const float* rb = RK + (long long)(n * 64) * 2112;

    // ---- prologue: stage Q transposed (+biases): Qw -> PS[q][dh], Qr -> BT[q][dh]
    {
        int r = t >> 4;
        int c4 = (t & 15) * 4;
        #pragma unroll
        for (int di = 0; di < 4; ++di) {
            int dh = r + di * 16;
            float4 v = *(const float4*)&qb[(long long)dh * 2048 + 1024 + i0 + c4];
            float bw = rwb[n * 64 + dh], br = rrb[n * 64 + dh];
            PS[c4 + 0][dh] = (__bf16)(v.x + bw);
            PS[c4 + 1][dh] = (__bf16)(v.y + bw);
            PS[c4 + 2][dh] = (__bf16)(v.z + bw);
            PS[c4 + 3][dh] = (__bf16)(v.w + bw);
            BT[c4 + 0][dh] = (__bf16)(v.x + br);
            BT[c4 + 1][dh] = (__bf16)(v.y + br);
            BT[c4 + 2][dh] = (__bf16)(v.z + br);
            BT[c4 + 3][dh] = (__bf16)(v.w + br);
        }
    }
    __syncthreads();
    bf16x8 qw0, qw1, qr0, qr1;
    {
        int mrow = w * 16 + l15;
        int k8 = lg * 8;
        qw0 = *(const bf16x8*)&PS[mrow][k8];
        qw1 = *(const bf16x8*)&PS[mrow][32 + k8];
        qr0 = *(const bf16x8*)&BT[mrow][k8];
        qr1 = *(const bf16x8*)&BT[mrow][32 + k8];
    }

    f32x4 O0 = {}, O1 = {}, O2 = {}, O3 = {};
    float rm[4] = {-1e30f, -1e30f, -1e30f, -1e30f};
    float rl[4] = {0.f, 0.f, 0.f, 0.f};

    for (int kt = 0; kt <= 16; ++kt) {
        const int j0 = i0 + kt * 64;
        const int pb = kt * 64 + 960;     // p = pb + (jc - ir + 63) = j - i + 1023
        __syncthreads();                  // previous iter's LDS reads done
        {
            int r = t >> 4, c4 = (t & 15) * 4;
            #pragma unroll
            for (int di = 0; di < 4; ++di) {
                int dh = r + di * 16;
                float4 kv = *(const float4*)&kb[(long long)dh * 2048 + j0 + c4];
                KT[c4 + 0][dh] = (__bf16)kv.x;
                KT[c4 + 1][dh] = (__bf16)kv.y;
                KT[c4 + 2][dh] = (__bf16)kv.z;
                KT[c4 + 3][dh] = (__bf16)kv.w;
                float4 vv = *(const float4*)&vb[(long long)dh * 2048 + j0 + c4];
                VS[dh][c4 + 0] = (__bf16)vv.x;
                VS[dh][c4 + 1] = (__bf16)vv.y;
                VS[dh][c4 + 2] = (__bf16)vv.z;
                VS[dh][c4 + 3] = (__bf16)vv.w;
                float4 r0 = *(const float4*)&rb[(long long)dh * 2112 + pb + c4];
                RT[c4 + 0][dh] = (__bf16)r0.x;
                RT[c4 + 1][dh] = (__bf16)r0.y;
                RT[c4 + 2][dh] = (__bf16)r0.z;
                RT[c4 + 3][dh] = (__bf16)r0.w;
                float4 r1 = *(const float4*)&rb[(long long)dh * 2112 + pb + 64 + c4];
                RT[64 + c4 + 0][dh] = (__bf16)r1.x;
                RT[64 + c4 + 1][dh] = (__bf16)r1.y;
                RT[64 + c4 + 2][dh] = (__bf16)r1.z;
                RT[64 + c4 + 3][dh] = (__bf16)r1.w;
            }
        }
        __syncthreads();

        // ---- BD_raw[own 16 q rows][128 p] -> BT (wave-private rows, no barrier needed)
        #pragma unroll
        for (int pt = 0; pt < 8; ++pt) {
            f32x4 c = {};
            c = __builtin_amdgcn_mfma_f32_16x16x32_bf16(qr0, *(const bf16x8*)&RT[pt * 16 + l15][lg * 8], c, 0, 0, 0);
            c = __builtin_amdgcn_mfma_f32_16x16x32_bf16(qr1, *(const bf16x8*)&RT[pt * 16 + l15][32 + lg * 8], c, 0, 0, 0);
            #pragma unroll
            for (int rg = 0; rg < 4; ++rg)
                BT[w * 16 + lg * 4 + rg][pt * 16 + l15] = (__bf16)c[rg];
        }

        // ---- AC + BD lookup + scale + band mask
        float sv[4][4];
        #pragma unroll
        for (int nt = 0; nt < 4; ++nt) {
            f32x4 c = {};
            c = __builtin_amdgcn_mfma_f32_16x16x32_bf16(qw0, *(const bf16x8*)&KT[nt * 16 + l15][lg * 8], c, 0, 0, 0);
            c = __builtin_amdgcn_mfma_f32_16x16x32_bf16(qw1, *(const bf16x8*)&KT[nt * 16 + l15][32 + lg * 8], c, 0, 0, 0);
            int jc = nt * 16 + l15;
            #pragma unroll
            for (int rg = 0; rg < 4; ++rg) {
                int ir = w * 16 + lg * 4 + rg;
                int dji = jc - ir;                               // j-i = 64*kt + dji
                float s = (c[rg] + (float)BT[ir][dji + 63]) * 0.125f;
                bool valid = (kt == 0) ? (dji >= 25)
                           : (kt == 1) ? (dji >= -39)
                           : (kt == 16) ? (dji <= 0) : true;
                sv[nt][rg] = valid ? s : -1e30f;
            }
        }

        // ---- online softmax (rows live in 16-lane groups)
        float fac[4], nm[4];
        #pragma unroll
        for (int rg = 0; rg < 4; ++rg) {
            float mx = fmaxf(fmaxf(sv[0][rg], sv[1][rg]), fmaxf(sv[2][rg], sv[3][rg]));
            mx = fmaxf(mx, __shfl_xor(mx, 1, 16));
            mx = fmaxf(mx, __shfl_xor(mx, 2, 16));
            mx = fmaxf(mx, __shfl_xor(mx, 4, 16));
            mx = fmaxf(mx, __shfl_xor(mx, 8, 16));
            nm[rg] = fmaxf(rm[rg], mx);
            fac[rg] = __expf(rm[rg] - nm[rg]);
            rm[rg] = nm[rg];
        }
        float ls[4] = {0.f, 0.f, 0.f, 0.f};
        #pragma unroll
        for (int nt = 0; nt < 4; ++nt) {
            int jc = nt * 16 + l15;
            #pragma unroll
            for (int rg = 0; rg < 4; ++rg) {
                float p = (sv[nt][rg] > -1e29f) ? __expf(sv[nt][rg] - nm[rg]) : 0.0f;
                ls[rg] += p;
                PS[w * 16 + lg * 4 + rg][jc] = (__bf16)p;
            }
        }
        #pragma unroll
        for (int rg = 0; rg < 4; ++rg) {
            float s2 = ls[rg];
            s2 += __shfl_xor(s2, 1, 16);
            s2 += __shfl_xor(s2, 2, 16);
            s2 += __shfl_xor(s2, 4, 16);
            s2 += __shfl_xor(s2, 8, 16);
            rl[rg] = rl[rg] * fac[rg] + s2;
            O0[rg] *= fac[rg]; O1[rg] *= fac[rg]; O2[rg] *= fac[rg]; O3[rg] *= fac[rg];
        }

        // ---- PV: O[q][dh] += P[q][j] * V[dh][j]
        bf16x8 pa0 = *(const bf16x8*)&PS[w * 16 + l15][lg * 8];
        bf16x8 pa1 = *(const bf16x8*)&PS[w * 16 + l15][32 + lg * 8];
        O0 = __builtin_amdgcn_mfma_f32_16x16x32_bf16(pa0, *(const bf16x8*)&VS[ 0 + l15][lg * 8], O0, 0, 0, 0);
        O0 = __builtin_amdgcn_mfma_f32_16x16x32_bf16(pa1, *(const bf16x8*)&VS[ 0 + l15][32 + lg * 8], O0, 0, 0, 0);
        O1 = __builtin_amdgcn_mfma_f32_16x16x32_bf16(pa0, *(const bf16x8*)&VS[16 + l15][lg * 8], O1, 0, 0, 0);
        O1 = __builtin_amdgcn_mfma_f32_16x16x32_bf16(pa1, *(const bf16x8*)&VS[16 + l15][32 + lg * 8], O1, 0, 0, 0);
        O2 = __builtin_amdgcn_mfma_f32_16x16x32_bf16(pa0, *(const bf16x8*)&VS[32 + l15][lg * 8], O2, 0, 0, 0);
        O2 = __builtin_amdgcn_mfma_f32_16x16x32_bf16(pa1, *(const bf16x8*)&VS[32 + l15][32 + lg * 8], O2, 0, 0, 0);
        O3 = __builtin_amdgcn_mfma_f32_16x16x32_bf16(pa0, *(const bf16x8*)&VS[48 + l15][lg * 8], O3, 0, 0, 0);
        O3 = __builtin_amdgcn_mfma_f32_16x16x32_bf16(pa1, *(const bf16x8*)&VS[48 + l15][32 + lg * 8], O3, 0, 0, 0);
    }

    // ---- epilogue: AV[b, n*64+dh, i0+q] = O/l
    #pragma unroll
    for (int rg = 0; rg < 4; ++rg) {
        float inv = 1.0f / rl[rg];
        int q = i0 + w * 16 + lg * 4 + rg;
        long long base = ((long long)b * 1024 + n * 64) * 1024 + q;
        AV[base + (long long)( 0 + l15) * 1024] = O0[rg] * inv;
        AV[base + (long long)(16 + l15) * 1024] = O1[rg] * inv;
        AV[base + (long long)(32 + l15) * 1024] = O2[rg] * inv;
        AV[base + (long long)(48 + l15) * 1024] = O3[rg] * inv;
    }
}

// ================= LN1 =================
__global__ __launch_bounds__(256) void ln1_kernel(
    const float* __restrict__ AO, const float* __restrict__ bo,
    const float* __restrict__ Z, float* __restrict__ H)
{
    int i = blockIdx.x, b = blockIdx.y, t = threadIdx.x;
    __shared__ float xs[D_MODEL];
    __shared__ float red[256];
    __shared__ float smu, srstd;
    long long base = (long long)b * D_MODEL * QLEN;

    float lsum = 0.0f;
    for (int dd = t; dd < D_MODEL; dd += 256) {
        float v = AO[base + (long long)dd * QLEN + i] + bo[dd] + Z[base + (long long)dd * QLEN + i];
        xs[dd] = v;
        lsum += v;
    }
    red[t] = lsum; __syncthreads();
    for (int s2 = 128; s2 > 0; s2 >>= 1) { if (t < s2) red[t] += red[t + s2]; __syncthreads(); }
    if (t == 0) smu = red[0] * (1.0f / D_MODEL);
    __syncthreads();
    float mu = smu;

    float lq = 0.0f;
    for (int dd = t; dd < D_MODEL; dd += 256) { float c = xs[dd] - mu; lq += c * c; }
    red[t] = lq; __syncthreads();
    for (int s2 = 128; s2 > 0; s2 >>= 1) { if (t < s2) red[t] += red[t + s2]; __syncthreads(); }
    if (t == 0) srstd = rsqrtf(red[0] * (1.0f / D_MODEL) + 1e-5f);
    __syncthreads();
    float rstd = srstd;

    for (int dd = t; dd < D_MODEL; dd += 256)
        H[base + (long long)i * D_MODEL + dd] = (xs[dd] - mu) * rstd;
}

// ================= LN2 =================
__global__ __launch_bounds__(256) void ln2_kernel(
    const float* __restrict__ F2, const float* __restrict__ H, float* __restrict__ OUT)
{
    int i = blockIdx.x, b = blockIdx.y, t = threadIdx.x;
    __shared__ float xs[D_MODEL];
    __shared__ float red[256];
    __shared__ float smu, srstd;
    long long base = (long long)b * D_MODEL * QLEN;

    float lsum = 0.0f;
    for (int dd = t; dd < D_MODEL; dd += 256) {
        float v = F2[base + (long long)i * D_MODEL + dd] + H[base + (long long)i * D_MODEL + dd];
        xs[dd] = v;
        lsum += v;
    }
    red[t] = lsum; __syncthreads();
    for (int s2 = 128; s2 > 0; s2 >>= 1) { if (t < s2) red[t] += red[t + s2]; __syncthreads(); }
    if (t == 0) smu = red[0] * (1.0f / D_MODEL);
    __syncthreads();
    float mu = smu;

    float lq = 0.0f;
    for (int dd = t; dd < D_MODEL; dd += 256) { float c = xs[dd] - mu; lq += c * c; }
    red[t] = lq; __syncthreads();
    for (int s2 = 128; s2 > 0; s2 >>= 1) { if (t < s2) red[t] += red[t + s2]; __syncthreads(); }
    if (t == 0) srstd = rsqrtf(red[0] * (1.0f / D_MODEL) + 1e-5f);
    __syncthreads();
    float rstd = srstd;

    for (int dd = t; dd < D_MODEL; dd += 256)
        OUT[base + (long long)dd * QLEN + i] = (xs[dd] - mu) * rstd;
}

// ================= launch =================
extern "C" void kernel_launch(void* const* d_in, const int* in_sizes, int n_in,
                              void* d_out, int out_size, void* d_ws, size_t ws_size,
                              hipStream_t stream) {
    const float* z    = (const float*)d_in[0];
    const float* zh   = (const float*)d_in[1];
    const float* u    = (const float*)d_in[2];
    const float* pos  = (const float*)d_in[3];
    const float* Wqkv = (const float*)d_in[4];
    const float* Wr   = (const float*)d_in[5];
    const float* rwb  = (const float*)d_in[6];
    const float* rrb  = (const float*)d_in[7];
    const float* Wo   = (const float*)d_in[8];
    const float* bo   = (const float*)d_in[9];
    const float* Wff1 = (const float*)d_in[10];
    const float* bff1 = (const float*)d_in[11];
    const float* Wff2 = (const float*)d_in[12];
    const float* bff2 = (const float*)d_in[13];
    float* out = (float*)d_out;
    float* ws  = (float*)d_ws;

    // workspace layout (floats). h/f1/f2 overlay wh (dead after attention).
    float* wh = ws;                        // (2,3072,2048) = 12,582,912
    float* rk = ws + 12582912;             // (1024,2112)   =  2,162,688
    float* av = ws + 14745600;             // (2,1024,1024)
    float* ao = ws + 16842752;             // (2,1024,1024)
    float* h  = ws;                        // overlays wh
    float* f1 = ws + 2097152;              // overlays wh
    float* f2 = ws + 10485760;             // overlays wh (ends at 12,582,912)

    const long long sZ  = (long long)D_MODEL * QLEN;
    const long long sWH = (long long)3072 * KLEN;
    const long long s1M = (long long)D_MODEL * QLEN;

    pad_zero<<<256, 256, 0, stream>>>(rk);
    gemm_nn_f32<<<dim3(16, 48, 2), 256, 0, stream>>>(
        Wqkv, zh, wh, u, 3072, 1024, 1024, 1024, 2048, 2048, 0LL, sZ, sWH);
    gemm_nn_f32<<<dim3(16, 48, 2), 256, 0, stream>>>(
        Wqkv, z, wh + 1024, u + 1024, 3072, 1024, 1024, 1024, 2048, 2048, 0LL, sZ, sWH);
    gemm_nn_f32<<<dim3(32, 16, 1), 256, 0, stream>>>(
        Wr, pos, rk, nullptr, 1024, 2048, 1024, 2048, 2112, 2048, 0LL, 0LL, 0LL);
    attn_mfma<<<512, 256, 0, stream>>>(wh, rk, rwb, rrb, av);
    gemm_nn_f32<<<dim3(16, 16, 2), 256, 0, stream>>>(
        Wo, av, ao, nullptr, 1024, 1024, 1024, 1024, 1024, 1024, 0LL, s1M, s1M);
    ln1_kernel<<<dim3(1024, 2), 256, 0, stream>>>(ao, bo, z, h);
    gemm_nt_f32<<<dim3(64, 32, 1), 256, 0, stream>>>(h, Wff1, f1, bff1, 2048, 4096, 1024, 1);
    gemm_nt_f32<<<dim3(16, 32, 1), 256, 0, stream>>>(f1, Wff2, f2, bff2, 2048, 1024, 4096, 0);
    ln2_kernel<<<dim3(1024, 2), 256, 0, stream>>>(f2, h, out);
}

// Round 3
// 412.560 us; speedup vs baseline: 10.2785x; 3.5793x over previous
//
#include <hip/hip_runtime.h>

#define D_MODEL 1024
#define QLEN 1024
#define MLEN 1024
#define KLEN 2048

typedef __bf16 bf16x8 __attribute__((ext_vector_type(8)));
typedef __bf16 bf16x4 __attribute__((ext_vector_type(4)));
typedef float f32x4 __attribute__((ext_vector_type(4)));

__device__ __forceinline__ void gload16(const void* g, void* l) {
    __builtin_amdgcn_global_load_lds(
        (const __attribute__((address_space(1))) void*)g,
        (__attribute__((address_space(3))) void*)l, 16, 0, 0);
}

// ============ bf16 MFMA GEMM: C[M,N] = A[M,K] @ Bt[N,K]^T (+U, +bias, relu) ============
// 4 waves in 2x2 grid. MT = m-frags per wave (BM = MT*32). BN=128, BK=64.
// LDS XOR-swizzle chunk c' = c ^ (row&7); staged linearly via pre-swizzled global source.
template<int MT>
__global__ __launch_bounds__(256) void gemm_bf16_k(
    const __bf16* __restrict__ A,   // [M][K]
    const __bf16* __restrict__ Bt,  // [N][K]
    float* __restrict__ C, __bf16* __restrict__ Cb,
    const float* __restrict__ U, const float* __restrict__ bias,
    int K, int ldC, int ldU, int relu,
    long long sB, long long sC, long long sU)
{
    __shared__ __bf16 As[MT * 32][64];
    __shared__ __bf16 Bs[128][64];

    const int bz = blockIdx.z;
    Bt += (long long)bz * sB;
    if (C)  C  += (long long)bz * sC;
    if (Cb) Cb += (long long)bz * sC;
    if (U)  U  += (long long)bz * sU;

    const int t = threadIdx.x;
    const int lane = t & 63, w = t >> 6;
    const int l15 = lane & 15, lg = lane >> 4;
    const int m0 = blockIdx.y * (MT * 32);
    const int n0 = blockIdx.x * 128;
    const int wm = w >> 1, wn = w & 1;

    const int srow = lane >> 3;   // 0..7
    const int cpr  = lane & 7;    // dest chunk'

    f32x4 acc[MT][4] = {};

    for (int k0 = 0; k0 < K; k0 += 64) {
        #pragma unroll
        for (int i = 0; i < MT; ++i) {
            int r = i * 32 + w * 8 + srow;
            int c = cpr ^ (r & 7);
            gload16(&A[(long long)(m0 + r) * K + k0 + c * 8], &As[i * 32 + w * 8][0]);
        }
        #pragma unroll
        for (int i = 0; i < 4; ++i) {
            int r = i * 32 + w * 8 + srow;
            int c = cpr ^ (r & 7);
            gload16(&Bt[(long long)(n0 + r) * K + k0 + c * 8], &Bs[i * 32 + w * 8][0]);
        }
        __syncthreads();
        #pragma unroll
        for (int kk = 0; kk < 2; ++kk) {
            bf16x8 bfr[4];
            #pragma unroll
            for (int nt = 0; nt < 4; ++nt) {
                int nr = wn * 64 + nt * 16 + l15;
                bfr[nt] = *(const bf16x8*)&Bs[nr][((kk * 4 + lg) ^ (nr & 7)) * 8];
            }
            #pragma unroll
            for (int mt = 0; mt < MT; ++mt) {
                int mr = wm * (MT * 16) + mt * 16 + l15;
                bf16x8 afr = *(const bf16x8*)&As[mr][((kk * 4 + lg) ^ (mr & 7)) * 8];
                #pragma unroll
                for (int nt = 0; nt < 4; ++nt)
                    acc[mt][nt] = __builtin_amdgcn_mfma_f32_16x16x32_bf16(afr, bfr[nt], acc[mt][nt], 0, 0, 0);
            }
        }
        __syncthreads();
    }

    #pragma unroll
    for (int mt = 0; mt < MT; ++mt) {
        #pragma unroll
        for (int nt = 0; nt < 4; ++nt) {
            #pragma unroll
            for (int rg = 0; rg < 4; ++rg) {
                int m = m0 + wm * (MT * 16) + mt * 16 + lg * 4 + rg;
                int n = n0 + wn * 64 + nt * 16 + l15;
                float v = acc[mt][nt][rg];
                if (U)    v += U[(long long)m * ldU + n];
                if (bias) v += bias[n];
                if (relu) v = fmaxf(v, 0.0f);
                if (Cb) Cb[(long long)m * ldC + n] = (__bf16)v;
                else    C [(long long)m * ldC + n] = v;
            }
        }
    }
}

// ============ fp32 -> bf16 elementwise convert (n % 4 == 0) ============
__global__ __launch_bounds__(256) void conv_bf16(
    const float* __restrict__ s, __bf16* __restrict__ d, int n)
{
    int i = (blockIdx.x * 256 + threadIdx.x) * 4;
    if (i < n) {
        float4 v = *(const float4*)&s[i];
        bf16x4 o = { (__bf16)v.x, (__bf16)v.y, (__bf16)v.z, (__bf16)v.w };
        *(bf16x4*)&d[i] = o;
    }
}

// ============ transpose-convert: S[R][Cc] fp32 -> D[Cc][R] bf16 ============
__global__ __launch_bounds__(256) void transp_bf16(
    const float* __restrict__ S, __bf16* __restrict__ D,
    int R, int Cc, long long sS, long long sD)
{
    S += (long long)blockIdx.z * sS;
    D += (long long)blockIdx.z * sD;
    __shared__ float ts[32][33];
    int r0 = blockIdx.y * 32, c0 = blockIdx.x * 32;
    int tr = threadIdx.x >> 5, tc = threadIdx.x & 31;
    #pragma unroll
    for (int p = 0; p < 4; ++p)
        ts[tr + p * 8][tc] = S[(long long)(r0 + tr + p * 8) * Cc + c0 + tc];
    __syncthreads();
    #pragma unroll
    for (int p = 0; p < 4; ++p)
        D[(long long)(c0 + tr + p * 8) * R + r0 + tc] = (__bf16)ts[tc][tr + p * 8];
}

// zero rk pad columns [2048, 2112)
__global__ __launch_bounds__(256) void pad_zero(float* __restrict__ rk) {
    int t = blockIdx.x * 256 + threadIdx.x;
    int row = t >> 6, c = t & 63;
    rk[(long long)row * 2112 + 2048 + c] = 0.0f;
}

// ================= MFMA flash attention (band j-i in [25,1024]) =================
__global__ __launch_bounds__(256) void attn_mfma(
    const float* __restrict__ WH, const float* __restrict__ RK,
    const float* __restrict__ rwb, const float* __restrict__ rrb,
    __bf16* __restrict__ AVt)       // out: (B, Q, 1024) token-major bf16
{
    __shared__ __bf16 KT[64][72];
    __shared__ __bf16 RT[128][72];
    __shared__ __bf16 VS[64][72];
    __shared__ __bf16 PS[64][72];
    __shared__ __bf16 BT[64][136];

    const int d = blockIdx.x;
    const int xcd = d & 7, idx = d >> 3;
    const int qt = idx & 15;
    const int gq = xcd + 8 * (idx >> 4);
    const int b = gq >> 4, n = gq & 15;
    const int i0 = qt * 64;

    const int t = threadIdx.x;
    const int lane = t & 63, w = t >> 6;
    const int l15 = lane & 15, lg = lane >> 4;

    const float* whb = WH + (long long)b * 3072 * 2048;
    const float* qb = whb + (long long)(n * 64) * 2048;
    const float* kb = whb + (long long)(1024 + n * 64) * 2048;
    const float* vb = whb + (long long)(2048 + n * 64) * 2048;
    const float* rb = RK + (long long)(n * 64) * 2112;

    {
        int r = t >> 4;
        int c4 = (t & 15) * 4;
        #pragma unroll
        for (int di = 0; di < 4; ++di) {
            int dh = r + di * 16;
            float4 v = *(const float4*)&qb[(long long)dh * 2048 + 1024 + i0 + c4];
            float bw = rwb[n * 64 + dh], br = rrb[n * 64 + dh];
            PS[c4 + 0][dh] = (__bf16)(v.x + bw);
            PS[c4 + 1][dh] = (__bf16)(v.y + bw);
            PS[c4 + 2][dh] = (__bf16)(v.z + bw);
            PS[c4 + 3][dh] = (__bf16)(v.w + bw);
            BT[c4 + 0][dh] = (__bf16)(v.x + br);
            BT[c4 + 1][dh] = (__bf16)(v.y + br);
            BT[c4 + 2][dh] = (__bf16)(v.z + br);
            BT[c4 + 3][dh] = (__bf16)(v.w + br);
        }
    }
    __syncthreads();
    bf16x8 qw0, qw1, qr0, qr1;
    {
        int mrow = w * 16 + l15;
        int k8 = lg * 8;
        qw0 = *(const bf16x8*)&PS[mrow][k8];
        qw1 = *(const bf16x8*)&PS[mrow][32 + k8];
        qr0 = *(const bf16x8*)&BT[mrow][k8];
        qr1 = *(const bf16x8*)&BT[mrow][32 + k8];
    }

    f32x4 O0 = {}, O1 = {}, O2 = {}, O3 = {};
    float rm[4] = {-1e30f, -1e30f, -1e30f, -1e30f};
    float rl[4] = {0.f, 0.f, 0.f, 0.f};

    for (int kt = 0; kt <= 16; ++kt) {
        const int j0 = i0 + kt * 64;
        const int pb = kt * 64 + 960;
        __syncthreads();
        {
            int r = t >> 4, c4 = (t & 15) * 4;
            #pragma unroll
            for (int di = 0; di < 4; ++di) {
                int dh = r + di * 16;
                float4 kv = *(const float4*)&kb[(long long)dh * 2048 + j0 + c4];
                KT[c4 + 0][dh] = (__bf16)kv.x;
                KT[c4 + 1][dh] = (__bf16)kv.y;
                KT[c4 + 2][dh] = (__bf16)kv.z;
                KT[c4 + 3][dh] = (__bf16)kv.w;
                float4 vv = *(const float4*)&vb[(long long)dh * 2048 + j0 + c4];
                VS[dh][c4 + 0] = (__bf16)vv.x;
                VS[dh][c4 + 1] = (__bf16)vv.y;
                VS[dh][c4 + 2] = (__bf16)vv.z;
                VS[dh][c4 + 3] = (__bf16)vv.w;
                float4 r0 = *(const float4*)&rb[(long long)dh * 2112 + pb + c4];
                RT[c4 + 0][dh] = (__bf16)r0.x;
                RT[c4 + 1][dh] = (__bf16)r0.y;
                RT[c4 + 2][dh] = (__bf16)r0.z;
                RT[c4 + 3][dh] = (__bf16)r0.w;
                float4 r1 = *(const float4*)&rb[(long long)dh * 2112 + pb + 64 + c4];
                RT[64 + c4 + 0][dh] = (__bf16)r1.x;
                RT[64 + c4 + 1][dh] = (__bf16)r1.y;
                RT[64 + c4 + 2][dh] = (__bf16)r1.z;
                RT[64 + c4 + 3][dh] = (__bf16)r1.w;
            }
        }
        __syncthreads();

        #pragma unroll
        for (int pt = 0; pt < 8; ++pt) {
            f32x4 c = {};
            c = __builtin_amdgcn_mfma_f32_16x16x32_bf16(qr0, *(const bf16x8*)&RT[pt * 16 + l15][lg * 8], c, 0, 0, 0);
            c = __builtin_amdgcn_mfma_f32_16x16x32_bf16(qr1, *(const bf16x8*)&RT[pt * 16 + l15][32 + lg * 8], c, 0, 0, 0);
            #pragma unroll
            for (int rg = 0; rg < 4; ++rg)
                BT[w * 16 + lg * 4 + rg][pt * 16 + l15] = (__bf16)c[rg];
        }

        float sv[4][4];
        #pragma unroll
        for (int nt = 0; nt < 4; ++nt) {
            f32x4 c = {};
            c = __builtin_amdgcn_mfma_f32_16x16x32_bf16(qw0, *(const bf16x8*)&KT[nt * 16 + l15][lg * 8], c, 0, 0, 0);
            c = __builtin_amdgcn_mfma_f32_16x16x32_bf16(qw1, *(const bf16x8*)&KT[nt * 16 + l15][32 + lg * 8], c, 0, 0, 0);
            int jc = nt * 16 + l15;
            #pragma unroll
            for (int rg = 0; rg < 4; ++rg) {
                int ir = w * 16 + lg * 4 + rg;
                int dji = jc - ir;
                float s = (c[rg] + (float)BT[ir][dji + 63]) * 0.125f;
                bool valid = (kt == 0) ? (dji >= 25)
                           : (kt == 1) ? (dji >= -39)
                           : (kt == 16) ? (dji <= 0) : true;
                sv[nt][rg] = valid ? s : -1e30f;
            }
        }

        float fac[4], nm[4];
        #pragma unroll
        for (int rg = 0; rg < 4; ++rg) {
            float mx = fmaxf(fmaxf(sv[0][rg], sv[1][rg]), fmaxf(sv[2][rg], sv[3][rg]));
            mx = fmaxf(mx, __shfl_xor(mx, 1, 16));
            mx = fmaxf(mx, __shfl_xor(mx, 2, 16));
            mx = fmaxf(mx, __shfl_xor(mx, 4, 16));
            mx = fmaxf(mx, __shfl_xor(mx, 8, 16));
            nm[rg] = fmaxf(rm[rg], mx);
            fac[rg] = __expf(rm[rg] - nm[rg]);
            rm[rg] = nm[rg];
        }
        float ls[4] = {0.f, 0.f, 0.f, 0.f};
        #pragma unroll
        for (int nt = 0; nt < 4; ++nt) {
            int jc = nt * 16 + l15;
            #pragma unroll
            for (int rg = 0; rg < 4; ++rg) {
                float p = (sv[nt][rg] > -1e29f) ? __expf(sv[nt][rg] - nm[rg]) : 0.0f;
                ls[rg] += p;
                PS[w * 16 + lg * 4 + rg][jc] = (__bf16)p;
            }
        }
        #pragma unroll
        for (int rg = 0; rg < 4; ++rg) {
            float s2 = ls[rg];
            s2 += __shfl_xor(s2, 1, 16);
            s2 += __shfl_xor(s2, 2, 16);
            s2 += __shfl_xor(s2, 4, 16);
            s2 += __shfl_xor(s2, 8, 16);
            rl[rg] = rl[rg] * fac[rg] + s2;
            O0[rg] *= fac[rg]; O1[rg] *= fac[rg]; O2[rg] *= fac[rg]; O3[rg] *= fac[rg];
        }

        bf16x8 pa0 = *(const bf16x8*)&PS[w * 16 + l15][lg * 8];
        bf16x8 pa1 = *(const bf16x8*)&PS[w * 16 + l15][32 + lg * 8];
        O0 = __builtin_amdgcn_mfma_f32_16x16x32_bf16(pa0, *(const bf16x8*)&VS[ 0 + l15][lg * 8], O0, 0, 0, 0);
        O0 = __builtin_amdgcn_mfma_f32_16x16x32_bf16(pa1, *(const bf16x8*)&VS[ 0 + l15][32 + lg * 8], O0, 0, 0, 0);
        O1 = __builtin_amdgcn_mfma_f32_16x16x32_bf16(pa0, *(const bf16x8*)&VS[16 + l15][lg * 8], O1, 0, 0, 0);
        O1 = __builtin_amdgcn_mfma_f32_16x16x32_bf16(pa1, *(const bf16x8*)&VS[16 + l15][32 + lg * 8], O1, 0, 0, 0);
        O2 = __builtin_amdgcn_mfma_f32_16x16x32_bf16(pa0, *(const bf16x8*)&VS[32 + l15][lg * 8], O2, 0, 0, 0);
        O2 = __builtin_amdgcn_mfma_f32_16x16x32_bf16(pa1, *(const bf16x8*)&VS[32 + l15][32 + lg * 8], O2, 0, 0, 0);
        O3 = __builtin_amdgcn_mfma_f32_16x16x32_bf16(pa0, *(const bf16x8*)&VS[48 + l15][lg * 8], O3, 0, 0, 0);
        O3 = __builtin_amdgcn_mfma_f32_16x16x32_bf16(pa1, *(const bf16x8*)&VS[48 + l15][32 + lg * 8], O3, 0, 0, 0);
    }

    // epilogue: AVt[b, q, feat] = bf16(O/l)  (token-major = Bt operand for Wo GEMM)
    #pragma unroll
    for (int rg = 0; rg < 4; ++rg) {
        float inv = 1.0f / rl[rg];
        int q = i0 + w * 16 + lg * 4 + rg;
        long long base = ((long long)b * 1024 + q) * 1024 + n * 64;
        AVt[base +  0 + l15] = (__bf16)(O0[rg] * inv);
        AVt[base + 16 + l15] = (__bf16)(O1[rg] * inv);
        AVt[base + 32 + l15] = (__bf16)(O2[rg] * inv);
        AVt[base + 48 + l15] = (__bf16)(O3[rg] * inv);
    }
}

// ================= LN1: h_bf[b*1024+i][:] = LN_d(ao + b_o + z) (token-major bf16) ==========
__global__ __launch_bounds__(256) void ln1_kernel(
    const float* __restrict__ AO, const float* __restrict__ bo,
    const float* __restrict__ Z, __bf16* __restrict__ Hb)
{
    int i = blockIdx.x, b = blockIdx.y, t = threadIdx.x;
    __shared__ float xs[D_MODEL];
    __shared__ float red[256];
    __shared__ float smu, srstd;
    long long base = (long long)b * D_MODEL * QLEN;

    float lsum = 0.0f;
    for (int dd = t; dd < D_MODEL; dd += 256) {
        float v = AO[base + (long long)dd * QLEN + i] + bo[dd] + Z[base + (long long)dd * QLEN + i];
        xs[dd] = v;
        lsum += v;
    }
    red[t] = lsum; __syncthreads();
    for (int s2 = 128; s2 > 0; s2 >>= 1) { if (t < s2) red[t] += red[t + s2]; __syncthreads(); }
    if (t == 0) smu = red[0] * (1.0f / D_MODEL);
    __syncthreads();
    float mu = smu;

    float lq = 0.0f;
    for (int dd = t; dd < D_MODEL; dd += 256) { float c = xs[dd] - mu; lq += c * c; }
    red[t] = lq; __syncthreads();
    for (int s2 = 128; s2 > 0; s2 >>= 1) { if (t < s2) red[t] += red[t + s2]; __syncthreads(); }
    if (t == 0) srstd = rsqrtf(red[0] * (1.0f / D_MODEL) + 1e-5f);
    __syncthreads();
    float rstd = srstd;

    long long ob = ((long long)b * 1024 + i) * 1024;
    for (int dd = t; dd < D_MODEL; dd += 256)
        Hb[ob + dd] = (__bf16)((xs[dd] - mu) * rstd);
}

// ================= LN2: out[b,d,i] = LN_d(f2 + h)[token, d], transposed write =================
__global__ __launch_bounds__(256) void ln2_kernel(
    const float* __restrict__ F2,      // [2048 tokens][1024]
    const __bf16* __restrict__ Hb,     // [2048 tokens][1024]
    float* __restrict__ OUT)           // (B,1024,Q)
{
    int i = blockIdx.x, b = blockIdx.y, t = threadIdx.x;
    __shared__ float xs[D_MODEL];
    __shared__ float red[256];
    __shared__ float smu, srstd;
    long long tb = ((long long)b * 1024 + i) * 1024;

    float lsum = 0.0f;
    for (int dd = t; dd < D_MODEL; dd += 256) {
        float v = F2[tb + dd] + (float)Hb[tb + dd];
        xs[dd] = v;
        lsum += v;
    }
    red[t] = lsum; __syncthreads();
    for (int s2 = 128; s2 > 0; s2 >>= 1) { if (t < s2) red[t] += red[t + s2]; __syncthreads(); }
    if (t == 0) smu = red[0] * (1.0f / D_MODEL);
    __syncthreads();
    float mu = smu;

    float lq = 0.0f;
    for (int dd = t; dd < D_MODEL; dd += 256) { float c = xs[dd] - mu; lq += c * c; }
    red[t] = lq; __syncthreads();
    for (int s2 = 128; s2 > 0; s2 >>= 1) { if (t < s2) red[t] += red[t + s2]; __syncthreads(); }
    if (t == 0) srstd = rsqrtf(red[0] * (1.0f / D_MODEL) + 1e-5f);
    __syncthreads();
    float rstd = srstd;

    long long base = (long long)b * D_MODEL * QLEN;
    for (int dd = t; dd < D_MODEL; dd += 256)
        OUT[base + (long long)dd * QLEN + i] = (xs[dd] - mu) * rstd;
}

// ================= launch =================
extern "C" void kernel_launch(void* const* d_in, const int* in_sizes, int n_in,
                              void* d_out, int out_size, void* d_ws, size_t ws_size,
                              hipStream_t stream) {
    const float* z    = (const float*)d_in[0];
    const float* zh   = (const float*)d_in[1];
    const float* u    = (const float*)d_in[2];
    const float* pos  = (const float*)d_in[3];
    const float* Wqkv = (const float*)d_in[4];
    const float* Wr   = (const float*)d_in[5];
    const float* rwb  = (const float*)d_in[6];
    const float* rrb  = (const float*)d_in[7];
    const float* Wo   = (const float*)d_in[8];
    const float* bo   = (const float*)d_in[9];
    const float* Wff1 = (const float*)d_in[10];
    const float* bff1 = (const float*)d_in[11];
    const float* Wff2 = (const float*)d_in[12];
    const float* bff2 = (const float*)d_in[13];
    float* out = (float*)d_out;
    float* ws  = (float*)d_ws;

    // ---- workspace (f32-slot offsets) ----
    float*  wh    = ws;                                  // (2,3072,2048) f32 : 12,582,912
    float*  rk    = ws + 12582912;                       // (1024,2112) f32   :  2,162,688
    __bf16* cat_t = (__bf16*)(ws + 14745600);            // (2,2048,1024) bf16:  2,097,152 slots
    __bf16* av_t  = (__bf16*)(ws + 14745600);            // overlays cat_t (dead after QKV)
    __bf16* pos_t = (__bf16*)(ws + 16842752);            // (2048,1024) bf16  :  1,048,576 slots
    __bf16* Wqkvb = (__bf16*)(ws + 17891328);            // 3,145,728 bf16    :  1,572,864
    __bf16* Wrb   = (__bf16*)(ws + 19464192);            //   524,288 slots
    __bf16* Wob   = (__bf16*)(ws + 19988480);
    __bf16* Wff1b = (__bf16*)(ws + 20512768);            // 2,097,152 slots
    __bf16* Wff2b = (__bf16*)(ws + 22609920);            // 2,097,152 slots
    float*  ao    = ws + 24707072;                       // (2,1024,1024) f32 -> ends 26,804,224
    // overlays inside wh (dead after attention):
    __bf16* h_bf  = (__bf16*)ws;                         // (2048,1024) bf16
    __bf16* f1b   = (__bf16*)(ws + 1048576);             // (2048,4096) bf16
    float*  f2    = ws + 5242880;                        // (2048,1024) f32

    // ---- converts & transposes ----
    conv_bf16<<<3072, 256, 0, stream>>>(Wqkv, Wqkvb, 3145728);
    conv_bf16<<<1024, 256, 0, stream>>>(Wr,   Wrb,   1048576);
    conv_bf16<<<1024, 256, 0, stream>>>(Wo,   Wob,   1048576);
    conv_bf16<<<4096, 256, 0, stream>>>(Wff1, Wff1b, 4194304);
    conv_bf16<<<4096, 256, 0, stream>>>(Wff2, Wff2b, 4194304);
    // cat_t[b][tok][d]: tok 0..1023 = zh^T, 1024..2047 = z^T
    transp_bf16<<<dim3(32, 32, 2), 256, 0, stream>>>(zh, cat_t,           1024, 1024, 1048576LL, 2097152LL);
    transp_bf16<<<dim3(32, 32, 2), 256, 0, stream>>>(z,  cat_t + 1048576, 1024, 1024, 1048576LL, 2097152LL);
    transp_bf16<<<dim3(64, 32, 1), 256, 0, stream>>>(pos, pos_t, 1024, 2048, 0LL, 0LL);
    pad_zero<<<256, 256, 0, stream>>>(rk);

    // ---- wh = Wqkv @ cat + u : M=3072 N=2048 K=1024, z=2 ----
    gemm_bf16_k<4><<<dim3(16, 24, 2), 256, 0, stream>>>(
        Wqkvb, cat_t, wh, nullptr, u, nullptr,
        1024, 2048, 2048, 0, 2097152LL, 6291456LL, 6291456LL);
    // ---- rk = Wr @ pos : M=1024 N=2048 K=1024, ldC=2112 ----
    gemm_bf16_k<2><<<dim3(16, 16, 1), 256, 0, stream>>>(
        Wrb, pos_t, rk, nullptr, nullptr, nullptr,
        1024, 2112, 0, 0, 0LL, 0LL, 0LL);
    // ---- attention -> av_t (bf16, token-major) ----
    attn_mfma<<<512, 256, 0, stream>>>(wh, rk, rwb, rrb, av_t);
    // ---- ao = Wo @ av : M=1024 N=1024 K=1024, z=2 ----
    gemm_bf16_k<2><<<dim3(8, 16, 2), 256, 0, stream>>>(
        Wob, av_t, ao, nullptr, nullptr, nullptr,
        1024, 1024, 0, 0, 1048576LL, 1048576LL, 0LL);
    // ---- h = LN(ao + bo + z) ----
    ln1_kernel<<<dim3(1024, 2), 256, 0, stream>>>(ao, bo, z, h_bf);
    // ---- f1 = relu(h @ Wff1^T + bff1) : M=2048 N=4096 K=1024, out bf16 ----
    gemm_bf16_k<4><<<dim3(32, 16, 1), 256, 0, stream>>>(
        h_bf, Wff1b, nullptr, f1b, nullptr, bff1,
        1024, 4096, 0, 1, 0LL, 0LL, 0LL);
    // ---- f2 = f1 @ Wff2^T + bff2 : M=2048 N=1024 K=4096, out f32 ----
    gemm_bf16_k<2><<<dim3(8, 32, 1), 256, 0, stream>>>(
        f1b, Wff2b, f2, nullptr, nullptr, bff2,
        4096, 1024, 0, 0, 0LL, 0LL, 0LL);
    // ---- out = LN(f2 + h) transposed ----
    ln2_kernel<<<dim3(1024, 2), 256, 0, stream>>>(f2, h_bf, out);
}